// Round 6
// baseline (105.719 us; speedup 1.0000x reference)
//
#include <hip/hip_runtime.h>

typedef float f4 __attribute__((ext_vector_type(4)));

// Problem constants (from reference)
#define BB 256      // batch (both expert and violator)
#define SS 2048     // sequence
#define DD 128      // feature dim
#define MARGIN 10.0f
#define ALPHA 3.0f
#define BETA 0.3f
#define GAMMA 0.3f

// ws layout (floats):
//   [0      .. 65535]  centroids: 512 rows x 128 (expert 0..255, violator 256..511)
//   [65536  .. 66047]  norms: 512 (||centroid||^2)
//   [66048  .. 66303]  sep partials: 256
#define WS_CENT   0
#define WS_NORMS  65536
#define WS_PART   66048

// Kernel 1: per (tensor,batch) centroid + squared norm.
// grid = 512, block = 1024 (16 waves). tid = ssub*32 + d4.
// A wave's load covers 1 KB contiguous. 4 independent accumulators; PLAIN
// loads this round (A/B vs round-5's nontemporal: NT reads may bypass the
// L2/L3 aggregation/MSHR path and cap read BW at ~6.1 TB/s).
__global__ __launch_bounds__(1024) void centroid_kernel(
    const float* __restrict__ E, const float* __restrict__ V,
    float* __restrict__ cent, float* __restrict__ norms)
{
    const int p = blockIdx.x;
    const float* src = (p < BB) ? (E + (size_t)p * SS * DD)
                                : (V + (size_t)(p - BB) * SS * DD);
    const f4* src4 = reinterpret_cast<const f4*>(src);

    const int tid  = threadIdx.x;
    const int d4   = tid & 31;   // float4 column 0..31
    const int ssub = tid >> 5;   // row slice 0..31

    const f4* p4 = src4 + (size_t)ssub * 32 + d4;
    f4 a0 = 0.f, a1 = 0.f, a2 = 0.f, a3 = 0.f;
    #pragma unroll 2
    for (int it = 0; it < 16; ++it) {
        f4 x0 = p4[0];
        f4 x1 = p4[1024];
        f4 x2 = p4[2048];
        f4 x3 = p4[3072];
        a0 += x0; a1 += x1; a2 += x2; a3 += x3;
        p4 += 4096;
    }
    f4 acc = (a0 + a1) + (a2 + a3);

    // lanes l and l+32 hold adjacent row-slices at the same d4 -> combine
    acc.x += __shfl_down(acc.x, 32);
    acc.y += __shfl_down(acc.y, 32);
    acc.z += __shfl_down(acc.z, 32);
    acc.w += __shfl_down(acc.w, 32);

    __shared__ f4 red[512];      // 16 waves x 32 columns
    if ((tid & 63) < 32) red[(tid >> 6) * 32 + (tid & 63)] = acc;
    __syncthreads();
    for (int h = 8; h >= 1; h >>= 1) {
        if (tid < h * 32) red[tid] += red[tid + h * 32];
        __syncthreads();
    }

    if (tid < 32) {
        f4 c = red[tid] * (1.0f / (float)SS);
        reinterpret_cast<f4*>(cent)[p * 32 + tid] = c;
        float n = c.x * c.x + c.y * c.y + c.z * c.z + c.w * c.w;
        n += __shfl_down(n, 16);
        n += __shfl_down(n, 8);
        n += __shfl_down(n, 4);
        n += __shfl_down(n, 2);
        n += __shfl_down(n, 1);
        if (tid == 0) norms[p] = n;
    }
}

// Kernel 2: block i computes sep_i = sum_j clamp(MARGIN - dist(e_i, v_j), 0)^2.
// One dot-product per thread; violator centroids (128 KB) stay L2-resident.
__global__ __launch_bounds__(256) void sep_kernel(
    const float* __restrict__ cent, const float* __restrict__ norms,
    float* __restrict__ partials)
{
    const int i = blockIdx.x;
    const int j = threadIdx.x;
    const f4* C4 = reinterpret_cast<const f4*>(cent);

    __shared__ f4 Ei[32];
    if (j < 32) Ei[j] = C4[i * 32 + j];
    __syncthreads();

    float dev = 0.f;
    #pragma unroll 8
    for (int q = 0; q < 32; ++q) {
        const f4 e  = Ei[q];
        const f4 vj = C4[(BB + j) * 32 + q];
        f4 t0 = e * vj;
        dev += t0.x + t0.y + t0.z + t0.w;
    }
    float sq_ev = fmaxf(norms[i] + norms[BB + j] - 2.0f * dev, 0.0f);
    float dist  = sqrtf(sq_ev + 1e-12f);
    float tt    = fmaxf(MARGIN - dist, 0.0f);
    float sep   = tt * tt;

    #pragma unroll
    for (int off = 32; off >= 1; off >>= 1) sep += __shfl_down(sep, off);
    __shared__ float wred[4];
    if ((j & 63) == 0) wred[j >> 6] = sep;
    __syncthreads();
    if (j == 0) partials[i] = wred[0] + wred[1] + wred[2] + wred[3];
}

// Kernel 3: finalize (1024 threads, f4-vectorized, latency-parallel).
// Clustering via closed form: sum_{i<j}||c_i-c_j||^2 = N*A - B,
//   A = sum_i ||c_i||^2, B = ||sum_i c_i||^2  (clamp never binds; absmax=0.0
//   validated rounds 2-5).
__global__ __launch_bounds__(1024) void finalize_kernel(
    const float* __restrict__ cent, const float* __restrict__ norms,
    const float* __restrict__ partials, float* __restrict__ out)
{
    const int tid = threadIdx.x;
    const f4* C4 = reinterpret_cast<const f4*>(cent);

    const int chunk = tid & 63;      // (half<<5) | d4
    const int r     = tid >> 6;      // 0..15 row-slice
    const int half  = chunk >> 5;
    const int d4    = chunk & 31;
    const f4* basep = C4 + (size_t)(half * BB) * 32 + d4;

    f4 cs = 0.f;
    #pragma unroll
    for (int k = 0; k < 16; ++k)
        cs += basep[(size_t)(r + k * 16) * 32];

    __shared__ f4 red[1024];         // [r][chunk]
    red[tid] = cs;
    __syncthreads();
    #pragma unroll
    for (int h = 8; h >= 1; h >>= 1) {
        if (tid < h * 64) red[tid] += red[tid + h * 64];
        __syncthreads();
    }

    __shared__ float Bvals[2];
    if (tid < 64) {
        f4 c = red[tid];             // colsum f4 for chunk tid
        float b = c.x * c.x + c.y * c.y + c.z * c.z + c.w * c.w;
        #pragma unroll
        for (int off = 16; off >= 1; off >>= 1)
            b += __shfl_down(b, off, 32);     // reduce within 32-lane halves
        if ((tid & 31) == 0) Bvals[tid >> 5] = b;   // lanes 0,32 (wave 0)
    }

    // A_e, A_v, SP reductions (threads 0..255 contribute)
    float a_e = 0.f, a_v = 0.f, sp = 0.f;
    if (tid < BB) {
        a_e = norms[tid];
        a_v = norms[BB + tid];
        sp  = partials[tid];
    }
    #pragma unroll
    for (int off = 32; off >= 1; off >>= 1) {
        a_e += __shfl_down(a_e, off);
        a_v += __shfl_down(a_v, off);
        sp  += __shfl_down(sp , off);
    }
    __shared__ float w3[16][3];
    if ((tid & 63) == 0) {
        w3[tid >> 6][0] = a_e;
        w3[tid >> 6][1] = a_v;
        w3[tid >> 6][2] = sp;
    }
    __syncthreads();

    if (tid == 0) {
        float A_e = w3[0][0] + w3[1][0] + w3[2][0] + w3[3][0];
        float A_v = w3[0][1] + w3[1][1] + w3[2][1] + w3[3][1];
        float SP  = w3[0][2] + w3[1][2] + w3[2][2] + w3[3][2];
        float B_e = Bvals[0];
        float B_v = Bvals[1];

        const float cnt = (float)(BB * (BB - 1) / 2);   // 32640
        float ee_sum = fmaxf((float)BB * A_e - B_e, 0.0f);
        float vv_sum = fmaxf((float)BB * A_v - B_v, 0.0f);
        float sep_mean = SP / (float)(BB * BB);
        out[0] = ALPHA * sep_mean + (BETA * ee_sum + GAMMA * vv_sum) / cnt;
    }
}

extern "C" void kernel_launch(void* const* d_in, const int* in_sizes, int n_in,
                              void* d_out, int out_size, void* d_ws, size_t ws_size,
                              hipStream_t stream) {
    const float* E = (const float*)d_in[0];
    const float* V = (const float*)d_in[1];
    float* ws   = (float*)d_ws;
    float* cent = ws + WS_CENT;
    float* nrm  = ws + WS_NORMS;
    float* part = ws + WS_PART;
    float* out  = (float*)d_out;

    centroid_kernel<<<512, 1024, 0, stream>>>(E, V, cent, nrm);
    sep_kernel<<<BB, 256, 0, stream>>>(cent, nrm, part);
    finalize_kernel<<<1, 1024, 0, stream>>>(cent, nrm, part, out);
}

// Round 7
// 94.235 us; speedup vs baseline: 1.1219x; 1.1219x over previous
//
#include <hip/hip_runtime.h>

typedef float f4 __attribute__((ext_vector_type(4)));

// Problem constants (from reference)
#define BB 256      // batch (both expert and violator)
#define SS 2048     // sequence
#define DD 128      // feature dim
#define MARGIN 10.0f
#define ALPHA 3.0f
#define BETA 0.3f
#define GAMMA 0.3f

// ws layout (floats):
//   [0      .. 65535]  centroids: 512 rows x 128 (expert 0..255, violator 256..511)
//   [65536  .. 66047]  norms: 512 (||centroid||^2)
//   [66048  .. 66303]  sep partials: 256
//   [66304  .. 66307]  AB: A_e, A_v, B_e, B_v
#define WS_CENT   0
#define WS_NORMS  65536
#define WS_PART   66048
#define WS_AB     66304

// Kernel 1: per (tensor,batch) centroid + squared norm.
// grid = 512, block = 1024 (16 waves). tid = ssub*32 + d4.
// A wave's load covers 1 KB contiguous. 4 independent accumulators.
// NONTEMPORAL loads: A/B-verified +8 us vs plain (rounds 5 vs 6) — stream-once
// data should bypass L2 allocation.
__global__ __launch_bounds__(1024) void centroid_kernel(
    const float* __restrict__ E, const float* __restrict__ V,
    float* __restrict__ cent, float* __restrict__ norms)
{
    const int p = blockIdx.x;
    const float* src = (p < BB) ? (E + (size_t)p * SS * DD)
                                : (V + (size_t)(p - BB) * SS * DD);
    const f4* src4 = reinterpret_cast<const f4*>(src);

    const int tid  = threadIdx.x;
    const int d4   = tid & 31;   // float4 column 0..31
    const int ssub = tid >> 5;   // row slice 0..31

    const f4* p4 = src4 + (size_t)ssub * 32 + d4;
    f4 a0 = 0.f, a1 = 0.f, a2 = 0.f, a3 = 0.f;
    #pragma unroll 2
    for (int it = 0; it < 16; ++it) {
        f4 x0 = __builtin_nontemporal_load(p4);
        f4 x1 = __builtin_nontemporal_load(p4 + 1024);
        f4 x2 = __builtin_nontemporal_load(p4 + 2048);
        f4 x3 = __builtin_nontemporal_load(p4 + 3072);
        a0 += x0; a1 += x1; a2 += x2; a3 += x3;
        p4 += 4096;
    }
    f4 acc = (a0 + a1) + (a2 + a3);

    // lanes l and l+32 hold adjacent row-slices at the same d4 -> combine
    acc.x += __shfl_down(acc.x, 32);
    acc.y += __shfl_down(acc.y, 32);
    acc.z += __shfl_down(acc.z, 32);
    acc.w += __shfl_down(acc.w, 32);

    __shared__ f4 red[512];      // 16 waves x 32 columns
    if ((tid & 63) < 32) red[(tid >> 6) * 32 + (tid & 63)] = acc;
    __syncthreads();
    for (int h = 8; h >= 1; h >>= 1) {
        if (tid < h * 32) red[tid] += red[tid + h * 32];
        __syncthreads();
    }

    if (tid < 32) {
        f4 c = red[tid] * (1.0f / (float)SS);
        reinterpret_cast<f4*>(cent)[p * 32 + tid] = c;
        float n = c.x * c.x + c.y * c.y + c.z * c.z + c.w * c.w;
        n += __shfl_down(n, 16);
        n += __shfl_down(n, 8);
        n += __shfl_down(n, 4);
        n += __shfl_down(n, 2);
        n += __shfl_down(n, 1);
        if (tid == 0) norms[p] = n;
    }
}

// Kernel 2: grid = 258 blocks x 256 threads.
//   blocks 0..255 : sep_i = sum_j clamp(MARGIN - dist(e_i, v_j), 0)^2
//   blocks 256,257: concurrent closed-form clustering inputs for half h:
//       A_h = sum_i ||c_i||^2,  B_h = ||sum_i c_i||^2
//   (runs hidden under the sep blocks; all reductions fixed-order.)
__global__ __launch_bounds__(256) void sep_colsum_kernel(
    const float* __restrict__ cent, const float* __restrict__ norms,
    float* __restrict__ partials, float* __restrict__ AB)
{
    const int bid = blockIdx.x;
    const int t   = threadIdx.x;
    const f4* C4  = reinterpret_cast<const f4*>(cent);

    if (bid < BB) {
        const int i = bid;
        __shared__ f4 Ei[32];
        if (t < 32) Ei[t] = C4[i * 32 + t];
        __syncthreads();

        float dev = 0.f;
        #pragma unroll 8
        for (int q = 0; q < 32; ++q) {
            const f4 e  = Ei[q];
            const f4 vj = C4[(BB + t) * 32 + q];
            f4 t0 = e * vj;
            dev += t0.x + t0.y + t0.z + t0.w;
        }
        float sq_ev = fmaxf(norms[i] + norms[BB + t] - 2.0f * dev, 0.0f);
        float dist  = sqrtf(sq_ev + 1e-12f);
        float tt    = fmaxf(MARGIN - dist, 0.0f);
        float sep   = tt * tt;

        #pragma unroll
        for (int off = 32; off >= 1; off >>= 1) sep += __shfl_down(sep, off);
        __shared__ float wred[4];
        if ((t & 63) == 0) wred[t >> 6] = sep;
        __syncthreads();
        if (t == 0) partials[i] = wred[0] + wred[1] + wred[2] + wred[3];
        return;
    }

    // ---- colsum block for half h (0 = expert, 1 = violator) ----
    const int h  = bid - BB;
    const int d4 = t & 31;       // f4 column chunk
    const int r  = t >> 5;       // row slice 0..7
    const f4* basep = C4 + (size_t)(h * BB) * 32 + d4;

    f4 cs = 0.f;
    #pragma unroll
    for (int k = 0; k < 32; ++k)
        cs += basep[(size_t)(r + k * 8) * 32];

    __shared__ f4 redc[256];     // [r][d4]
    redc[t] = cs;
    __syncthreads();
    #pragma unroll
    for (int hh = 4; hh >= 1; hh >>= 1) {
        if (t < hh * 32) redc[t] += redc[t + hh * 32];
        __syncthreads();
    }

    __shared__ float Bsh;
    if (t < 32) {
        f4 c = redc[t];
        float b = c.x * c.x + c.y * c.y + c.z * c.z + c.w * c.w;
        #pragma unroll
        for (int off = 16; off >= 1; off >>= 1) b += __shfl_down(b, off, 32);
        if (t == 0) Bsh = b;
    }

    float a = norms[h * BB + t];
    #pragma unroll
    for (int off = 32; off >= 1; off >>= 1) a += __shfl_down(a, off);
    __shared__ float wa[4];
    if ((t & 63) == 0) wa[t >> 6] = a;
    __syncthreads();
    if (t == 0) {
        AB[h]     = wa[0] + wa[1] + wa[2] + wa[3];   // A_h
        AB[2 + h] = Bsh;                             // B_h
    }
}

// Kernel 3: tiny finalize — reduce 256 sep partials, combine with A/B.
//   sum_{i<j}||c_i-c_j||^2 = N*A - B  (clamp never binds; absmax=0.0
//   validated rounds 2-6).
__global__ __launch_bounds__(256) void finalize_kernel(
    const float* __restrict__ partials, const float* __restrict__ AB,
    float* __restrict__ out)
{
    const int t = threadIdx.x;
    float sp = partials[t];
    #pragma unroll
    for (int off = 32; off >= 1; off >>= 1) sp += __shfl_down(sp, off);
    __shared__ float w[4];
    if ((t & 63) == 0) w[t >> 6] = sp;
    __syncthreads();
    if (t == 0) {
        float SP  = w[0] + w[1] + w[2] + w[3];
        float A_e = AB[0], A_v = AB[1], B_e = AB[2], B_v = AB[3];
        const float cnt = (float)(BB * (BB - 1) / 2);   // 32640
        float ee_sum = fmaxf((float)BB * A_e - B_e, 0.0f);
        float vv_sum = fmaxf((float)BB * A_v - B_v, 0.0f);
        float sep_mean = SP / (float)(BB * BB);
        out[0] = ALPHA * sep_mean + (BETA * ee_sum + GAMMA * vv_sum) / cnt;
    }
}

extern "C" void kernel_launch(void* const* d_in, const int* in_sizes, int n_in,
                              void* d_out, int out_size, void* d_ws, size_t ws_size,
                              hipStream_t stream) {
    const float* E = (const float*)d_in[0];
    const float* V = (const float*)d_in[1];
    float* ws   = (float*)d_ws;
    float* cent = ws + WS_CENT;
    float* nrm  = ws + WS_NORMS;
    float* part = ws + WS_PART;
    float* ab   = ws + WS_AB;
    float* out  = (float*)d_out;

    centroid_kernel<<<512, 1024, 0, stream>>>(E, V, cent, nrm);
    sep_colsum_kernel<<<BB + 2, 256, 0, stream>>>(cent, nrm, part, ab);
    finalize_kernel<<<1, 256, 0, stream>>>(part, ab, out);
}